// Round 14
// baseline (754.577 us; speedup 1.0000x reference)
//
#include <hip/hip_runtime.h>
#include <hip/hip_bf16.h>
#include <math.h>

typedef short s8v __attribute__((ext_vector_type(8)));
typedef float f32x4 __attribute__((ext_vector_type(4)));
typedef unsigned u32x4 __attribute__((ext_vector_type(4)));

__device__ __forceinline__ ushort f2bf(float f) {
    __hip_bfloat16 h = __float2bfloat16(f);
    return *reinterpret_cast<ushort*>(&h);
}
__device__ __forceinline__ float bf2f(ushort u) {
    return __uint_as_float(((unsigned)u) << 16);
}
__device__ __forceinline__ unsigned pack_split(float v) {
    ushort h = f2bf(v);
    ushort l = f2bf(v - bf2f(h));
    return ((unsigned)h << 16) | (unsigned)l;
}
__device__ __forceinline__ float unpack_f(unsigned p) {
    return __uint_as_float(p & 0xffff0000u) + __uint_as_float(p << 16);
}
__device__ __forceinline__ void gload16(const void* g, void* l) {
    __builtin_amdgcn_global_load_lds(
        (const __attribute__((address_space(1))) void*)g,
        (__attribute__((address_space(3))) void*)l, 16, 0, 0);
}
__device__ __forceinline__ unsigned lds_addr(const void* p) {
    return (unsigned)(size_t)(const __attribute__((address_space(3))) void*)p;
}
// 8 packed u32 (k0..7) -> hi frag / lo frag
__device__ __forceinline__ void unpack8(const u32x4 p0, const u32x4 p1, s8v& hi, s8v& lo) {
    union { s8v v; unsigned u[4]; } H, L;
    H.u[0] = (p0[0] >> 16) | (p0[1] & 0xffff0000u);
    H.u[1] = (p0[2] >> 16) | (p0[3] & 0xffff0000u);
    H.u[2] = (p1[0] >> 16) | (p1[1] & 0xffff0000u);
    H.u[3] = (p1[2] >> 16) | (p1[3] & 0xffff0000u);
    L.u[0] = (p0[0] & 0xffffu) | (p0[1] << 16);
    L.u[1] = (p0[2] & 0xffffu) | (p0[3] << 16);
    L.u[2] = (p1[0] & 0xffffu) | (p1[1] << 16);
    L.u[3] = (p1[2] & 0xffffu) | (p1[3] << 16);
    hi = H.v; lo = L.v;
}
// 8 fp32 -> hi/lo bf16 frags (stem GEMM1 only)
__device__ __forceinline__ void cvt8(const u32x4 p0, const u32x4 p1, s8v& hi, s8v& lo) {
    union { s8v v; ushort e[8]; } H, L;
    float f[8] = {__uint_as_float(p0[0]), __uint_as_float(p0[1]),
                  __uint_as_float(p0[2]), __uint_as_float(p0[3]),
                  __uint_as_float(p1[0]), __uint_as_float(p1[1]),
                  __uint_as_float(p1[2]), __uint_as_float(p1[3])};
    #pragma unroll
    for (int e = 0; e < 8; ++e) {
        ushort h = f2bf(f[e]);
        H.e[e] = (ushort)h;
        L.e[e] = f2bf(f[e] - bf2f(h));
    }
    hi = H.v; lo = L.v;
}
template<bool AF32>
__device__ __forceinline__ void frag_a(const u32x4 p0, const u32x4 p1, s8v& hi, s8v& lo) {
    if constexpr (AF32) cvt8(p0, p1, hi, lo);
    else                unpack8(p0, p1, hi, lo);
}

#define DSR(dst, addr, OFF) \
    asm volatile("ds_read_b128 %0, %1 offset:" #OFF : "=v"(dst) : "v"(addr))

// B fragment direct from global (L2-resident weights), SGPR base + VGPR voffset
#define GLB(dst, voff, base, OFF) \
    asm volatile("global_load_dwordx4 %0, %1, %2 offset:" #OFF \
                 : "=v"(dst) : "v"(voff), "s"(base))

#define TRI(ah, al, bh, bl, C) \
    C = __builtin_amdgcn_mfma_f32_16x16x32_bf16(ah, bh, C, 0, 0, 0); \
    C = __builtin_amdgcn_mfma_f32_16x16x32_bf16(ah, bl, C, 0, 0, 0); \
    C = __builtin_amdgcn_mfma_f32_16x16x32_bf16(al, bh, C, 0, 0, 0);

// ---------------- CSR build ----------------

__global__ __launch_bounds__(256)
void hist_kernel(const int* __restrict__ dst, int* __restrict__ cnt, int E) {
    int e = blockIdx.x * 256 + threadIdx.x;
    if (e < E) atomicAdd(&cnt[dst[e]], 1);
}

__global__ __launch_bounds__(256)
void scan_part(const int* __restrict__ cnt, int* __restrict__ bsum, int n) {
    __shared__ int s[256];
    int b = blockIdx.x, t = threadIdx.x;
    int i0 = b * 1024 + t * 4;
    int v = 0;
    if (i0 + 3 < n) {
        int4 q = *(const int4*)(cnt + i0);
        v = q.x + q.y + q.z + q.w;
    } else {
        for (int i = 0; i < 4; ++i) if (i0 + i < n) v += cnt[i0 + i];
    }
    s[t] = v;
    __syncthreads();
    for (int d = 128; d > 0; d >>= 1) {
        if (t < d) s[t] += s[t + d];
        __syncthreads();
    }
    if (t == 0) bsum[b] = s[0];
}

__global__ __launch_bounds__(64)
void scan_top(int* __restrict__ bsum, int nb) {
    int l = threadIdx.x;
    int own = (l < nb) ? bsum[l] : 0;
    int v = own;
    #pragma unroll
    for (int d = 1; d < 64; d <<= 1) {
        int u = __shfl_up(v, d, 64);
        if (l >= d) v += u;
    }
    if (l < nb) bsum[l] = v - own;   // exclusive
}

__global__ __launch_bounds__(256)
void scan_final(const int* __restrict__ cnt, const int* __restrict__ bsum,
                int* __restrict__ off, int n, int E) {
    __shared__ int s[256];
    int b = blockIdx.x, t = threadIdx.x;
    int i0 = b * 1024 + t * 4;
    int v0 = 0, v1 = 0, v2 = 0, v3 = 0;
    if (i0 + 3 < n) {
        int4 q = *(const int4*)(cnt + i0);
        v0 = q.x; v1 = q.y; v2 = q.z; v3 = q.w;
    } else {
        if (i0     < n) v0 = cnt[i0];
        if (i0 + 1 < n) v1 = cnt[i0 + 1];
        if (i0 + 2 < n) v2 = cnt[i0 + 2];
        if (i0 + 3 < n) v3 = cnt[i0 + 3];
    }
    int tsum = v0 + v1 + v2 + v3;
    s[t] = tsum;
    __syncthreads();
    for (int d = 1; d < 256; d <<= 1) {
        int u = (t >= d) ? s[t - d] : 0;
        __syncthreads();
        s[t] += u;
        __syncthreads();
    }
    int excl = s[t] - tsum + bsum[b];
    if (i0     < n) off[i0]     = excl;
    if (i0 + 1 < n) off[i0 + 1] = excl + v0;
    if (i0 + 2 < n) off[i0 + 2] = excl + v0 + v1;
    if (i0 + 3 < n) off[i0 + 3] = excl + v0 + v1 + v2;
    if (b == 0 && t == 0) off[n] = E;
}

__global__ __launch_bounds__(256)
void scatter_kernel(const int* __restrict__ src, const int* __restrict__ dst,
                    int* __restrict__ cur, const int* __restrict__ off,
                    int* __restrict__ csr, int E) {
    int e = blockIdx.x * 256 + threadIdx.x;
    if (e < E) {
        int d = dst[e];
        int pos = off[d] + atomicAdd(&cur[d], 1);
        csr[pos] = src[e];
    }
}

// ------- weight prep: planar-chunked hi/lo bf16, [k/8][n][8], concat along K --

struct PrepW {
    const float* W[12];
    ushort* H[12];
    ushort* L[12];
    int end[12];
    int koff[12];
    int nshift[12];
};

__global__ __launch_bounds__(256)
void prep_weights(PrepW a, int total) {
    int id = blockIdx.x * 256 + threadIdx.x;
    if (id >= total) return;
    int s = 0;
    #pragma unroll
    for (int i = 0; i < 12; ++i) if (id >= a.end[i]) s = i + 1;
    int base = (s == 0) ? 0 : a.end[s - 1];
    int e = id - base;
    int Nmask = (1 << a.nshift[s]) - 1;
    int n = e & Nmask;
    int k = e >> a.nshift[s];
    float w = a.W[s][(size_t)k * (Nmask + 1) + n];
    ushort hi = f2bf(w);
    int kp = a.koff[s] + k;
    size_t idx = ((size_t)(kp >> 3) * (Nmask + 1) + n) * 8 + (kp & 7);
    a.H[s][idx] = hi;
    a.L[s][idx] = f2bf(w - bf2f(hi));
}

// ---------------- per-dst softmax aggregation (packed u32, direct exp) -------

__global__ __launch_bounds__(256)
void sage_aggr_pk(const unsigned* __restrict__ X, const int* __restrict__ csr,
                  const int* __restrict__ off, unsigned* __restrict__ O, int nN) {
    int node = blockIdx.x * 4 + (threadIdx.x >> 6);
    if (node >= nN) return;
    int c4 = (threadIdx.x & 63) * 4;
    int s0 = off[node], s1 = off[node + 1];
    float se0 = 0, se1 = 0, se2 = 0, se3 = 0;
    float sm0 = 0, sm1 = 0, sm2 = 0, sm3 = 0;
    for (int j = s0; j < s1; ++j) {
        uint4 p = *(const uint4*)(X + (size_t)csr[j] * 256 + c4);
        float v0 = unpack_f(p.x), v1 = unpack_f(p.y), v2 = unpack_f(p.z), v3 = unpack_f(p.w);
        float e0 = __expf(fminf(v0, 60.f));
        float e1 = __expf(fminf(v1, 60.f));
        float e2 = __expf(fminf(v2, 60.f));
        float e3 = __expf(fminf(v3, 60.f));
        se0 += e0; sm0 = fmaf(v0, e0, sm0);
        se1 += e1; sm1 = fmaf(v1, e1, sm1);
        se2 += e2; sm2 = fmaf(v2, e2, sm2);
        se3 += e3; sm3 = fmaf(v3, e3, sm3);
    }
    uint4 o;
    o.x = pack_split((s1 > s0) ? sm0 / se0 : 0.f);
    o.y = pack_split((s1 > s0) ? sm1 / se1 : 0.f);
    o.z = pack_split((s1 > s0) ? sm2 / se2 : 0.f);
    o.w = pack_split((s1 > s0) ? sm3 / se3 : 0.f);
    *(uint4*)(O + (size_t)node * 256 + c4) = o;
}

// ---------------- split-bf16 MFMA GEMM: A via LDS (2 bufs), B global->reg -----
// Round-13 structure with the race FIX: each wave drains its own A(t)
// stage-writes (vmcnt(8)) BEFORE s_barrier, so the barrier publishes all
// waves' LDS writes before any wave reads buf(t). (Round 13 had vmcnt after
// the barrier -> wave Y could read wave X's rows before X's gload_lds
// landed.) LDS 2 bufs x 16KB = 32KB -> 4 blocks/CU.
// Per step: vmcnt(8); barrier; DSR A0; STAGE(t+1); DSR A1; vmcnt(4)+
// lgkmcnt(2) [B(t) in regs, A(t+1) flying]; MFMA clusters with
// lgkmcnt-interleaved A reads; issue B(t+1) last.

template<int NT1, int NT2, bool AF32, int NB, bool DOTANH>
__global__ __launch_bounds__(256, 4)
void gemm_pipe(const float* __restrict__ Af,
               const unsigned* __restrict__ A1, const unsigned* __restrict__ A2,
               const ushort* __restrict__ BH, const ushort* __restrict__ BL,
               const float* __restrict__ bias,
               unsigned* __restrict__ Cpk, float* __restrict__ Cf, int M) {
    constexpr int NT = NT1 + NT2;
    constexpr int KU = NT * 32;
    constexpr int NCB = NB / 128;
    constexpr unsigned DSTEP = 4u * NB * 16u;   // bv advance per K-step (bytes)
    __shared__ unsigned lds[2][4096];           // 2 x 16KB, A only

    const int tid = threadIdx.x;
    const int l = tid & 63;
    const int w = tid >> 6;               // 0..3
    const int wm = w >> 1, wn = w & 1;
    const int li = l & 15, kq = l >> 4;
    const int b = blockIdx.x;
    const int bm = (b / NCB) * 128;
    const int bn = (b % NCB) * 128;

    const int srow8 = l >> 3;
    const int schunk = (l & 7) ^ srow8;   // swizzled source k-chunk

    const unsigned lbase = lds_addr(&lds[0][0]);
    const unsigned aoff = (unsigned)((wm * 64 + li) * 128 + (((2 * kq) ^ (li & 7)) * 16));

    f32x4 acc[4][4];
    #pragma unroll
    for (int i = 0; i < 4; ++i)
        #pragma unroll
        for (int j = 0; j < 4; ++j) acc[i][j] = (f32x4){0.f, 0.f, 0.f, 0.f};

    auto STAGE = [&](int t, int buf) {
        #pragma unroll
        for (int s = 0; s < 4; ++s) {         // A: 128 rows, wave w owns 32
            int r = 32 * w + 8 * s + srow8;
            int gr = bm + r; gr = (gr < M) ? gr : (M - 1);
            const void* src;
            if constexpr (AF32) {
                src = Af + (size_t)gr * KU + t * 32 + schunk * 4;
            } else if constexpr (NT2 > 0) {
                src = (t < NT1) ? (const void*)(A1 + (size_t)gr * (NT1 * 32) + t * 32 + schunk * 4)
                                : (const void*)(A2 + (size_t)gr * (NT2 * 32) + (t - NT1) * 32 + schunk * 4);
            } else {
                src = A1 + (size_t)gr * KU + t * 32 + schunk * 4;
            }
            gload16(src, &lds[buf][(32 * w + 8 * s) * 32 + l * 4]);
        }
    };

    // B voffset: element (kchunk*NB + n) * 16B; kchunk = t*4 + kq
    unsigned bv = (unsigned)((kq * NB + bn + wn * 64 + li) * 16);
    s8v bh0, bh1, bh2, bh3, bl0, bl1, bl2, bl3;

    // prologue: A(0) staged (4 loads); B(0) in flight (8 loads)
    STAGE(0, 0);
    GLB(bh0, bv, BH, 0);   GLB(bh1, bv, BH, 256);
    GLB(bh2, bv, BH, 512); GLB(bh3, bv, BH, 768);
    GLB(bl0, bv, BL, 0);   GLB(bl1, bv, BL, 256);
    GLB(bl2, bv, BL, 512); GLB(bl3, bv, BL, 768);
    bv += DSTEP;

    #pragma unroll
    for (int t = 0; t < NT; ++t) {
        // FIX: drain own A(t) writes BEFORE the barrier; barrier then
        // publishes all waves' A(t) LDS writes.
        asm volatile("s_waitcnt vmcnt(8)" ::: "memory");
        __builtin_amdgcn_s_barrier();
        __builtin_amdgcn_sched_barrier(0);

        const int buf = t & 1;
        unsigned ab = lbase + (unsigned)buf * 16384u + aoff;
        unsigned ab1 = ab ^ 16u;

        u32x4 A0, A4, A1v, A5, A2v, A6, A3, A7;
        DSR(A0, ab, 0); DSR(A4, ab1, 0);
        __builtin_amdgcn_sched_barrier(0);

        if (t + 1 < NT) STAGE(t + 1, buf ^ 1);
        __builtin_amdgcn_sched_barrier(0);

        DSR(A1v, ab, 2048); DSR(A5, ab1, 2048);
        // drain B(t); keep A(t+1) in flight; A0/A4 returned
        if (t + 1 < NT) asm volatile("s_waitcnt vmcnt(4) lgkmcnt(2)" ::: "memory");
        else            asm volatile("s_waitcnt vmcnt(0) lgkmcnt(2)" ::: "memory");
        __builtin_amdgcn_sched_barrier(0);

        __builtin_amdgcn_s_setprio(1);
        {
            s8v ah, al;
            frag_a<AF32>(A0, A4, ah, al);
            TRI(ah, al, bh0, bl0, acc[0][0]) TRI(ah, al, bh1, bl1, acc[0][1])
            TRI(ah, al, bh2, bl2, acc[0][2]) TRI(ah, al, bh3, bl3, acc[0][3])
        }
        __builtin_amdgcn_sched_barrier(0);
        DSR(A2v, ab, 4096); DSR(A6, ab1, 4096);
        asm volatile("s_waitcnt lgkmcnt(2)" ::: "memory");
        __builtin_amdgcn_sched_barrier(0);
        {
            s8v ah, al;
            frag_a<AF32>(A1v, A5, ah, al);
            TRI(ah, al, bh0, bl0, acc[1][0]) TRI(ah, al, bh1, bl1, acc[1][1])
            TRI(ah, al, bh2, bl2, acc[1][2]) TRI(ah, al, bh3, bl3, acc[1][3])
        }
        __builtin_amdgcn_sched_barrier(0);
        DSR(A3, ab, 6144); DSR(A7, ab1, 6144);
        asm volatile("s_waitcnt lgkmcnt(2)" ::: "memory");
        __builtin_amdgcn_sched_barrier(0);
        {
            s8v ah, al;
            frag_a<AF32>(A2v, A6, ah, al);
            TRI(ah, al, bh0, bl0, acc[2][0]) TRI(ah, al, bh1, bl1, acc[2][1])
            TRI(ah, al, bh2, bl2, acc[2][2]) TRI(ah, al, bh3, bl3, acc[2][3])
        }
        asm volatile("s_waitcnt lgkmcnt(0)" ::: "memory");
        __builtin_amdgcn_sched_barrier(0);
        {
            s8v ah, al;
            frag_a<AF32>(A3, A7, ah, al);
            TRI(ah, al, bh0, bl0, acc[3][0]) TRI(ah, al, bh1, bl1, acc[3][1])
            TRI(ah, al, bh2, bl2, acc[3][2]) TRI(ah, al, bh3, bl3, acc[3][3])
        }
        __builtin_amdgcn_s_setprio(0);
        __builtin_amdgcn_sched_barrier(0);

        if (t + 1 < NT) {   // issue B(t+1); lands before next step's vmcnt(4)
            GLB(bh0, bv, BH, 0);   GLB(bh1, bv, BH, 256);
            GLB(bh2, bv, BH, 512); GLB(bh3, bv, BH, 768);
            GLB(bl0, bv, BL, 0);   GLB(bl1, bv, BL, 256);
            GLB(bl2, bv, BL, 512); GLB(bl3, bv, BL, 768);
            bv += DSTEP;
        }
    }

    // epilogue. C frag: col = lane&15, row = (lane>>4)*4 + reg
    #pragma unroll
    for (int j = 0; j < 4; ++j) {
        int col = bn + wn * 64 + 16 * j + li;
        float bb = bias[col];
        #pragma unroll
        for (int i = 0; i < 4; ++i) {
            int row0 = bm + wm * 64 + 16 * i + kq * 4;
            #pragma unroll
            for (int r = 0; r < 4; ++r) {
                float v = acc[i][j][r] + bb;
                if constexpr (DOTANH) {
                    if (row0 + r < M)
                        Cf[(size_t)(row0 + r) * NB + col] = tanhf(v);
                } else {
                    Cpk[(size_t)(row0 + r) * 256 + col] = pack_split(fmaxf(v, 0.f));
                }
            }
        }
    }
}

// ---------------- launch ----------------

extern "C" void kernel_launch(void* const* d_in, const int* in_sizes, int n_in,
                              void* d_out, int out_size, void* d_ws, size_t ws_size,
                              hipStream_t stream) {
    const float* feat = (const float*)d_in[0];
    const int* einfo = (const int*)d_in[1];
    const float* b1 = (const float*)d_in[3];
    const float* b2 = (const float*)d_in[5];
    const float* b3 = (const float*)d_in[7];
    const float* bl1 = (const float*)d_in[9];
    const float* blH = (const float*)d_in[12];
    const float* bl2 = (const float*)d_in[15];
    const float* bp1 = (const float*)d_in[18];
    const float* bp2 = (const float*)d_in[20];
    const float* bp3 = (const float*)d_in[22];

    const int IN_DIM = 512;
    const int N = in_sizes[0] / IN_DIM;   // 50000
    const int E = in_sizes[1] / 2;        // 400000
    const int* src = einfo;
    const int* dst = einfo + E;
    const int M_pad = ((N + 127) / 128) * 128;      // 50176
    const size_t PLANE_U = (size_t)M_pad * 256;

    unsigned* P0 = (unsigned*)d_ws;
    unsigned* P1 = P0 + PLANE_U;
    unsigned* P2 = P1 + PLANE_U;
    ushort* W = (ushort*)(P2 + PLANE_U);

    // planar-chunked weight planes (concat along K for fused SAGE GEMMs)
    const int gsz[9] = {131072, 65536, 65536, 131072, 131072, 131072, 65536, 65536, 32768};
    ushort* GH[9]; ushort* GL[9];
    for (int i = 0; i < 9; ++i) { GH[i] = W; W += gsz[i]; GL[i] = W; W += gsz[i]; }

    const int widx[12]   = {2, 4, 6, 8, 10, 11, 13, 14, 16, 17, 19, 21};
    const int wplane[12] = {0, 1, 2, 3, 3, 4, 4, 5, 5, 6, 7, 8};
    const int wkoff[12]  = {0, 0, 0, 0, 256, 0, 256, 0, 256, 0, 0, 0};
    const int wnsh[12]   = {8, 8, 8, 8, 8, 8, 8, 8, 8, 8, 8, 7};
    const int welem[12]  = {131072, 65536, 65536, 65536, 65536, 65536, 65536,
                            65536, 65536, 65536, 65536, 32768};

    PrepW pa;
    int acc_end = 0;
    for (int i = 0; i < 12; ++i) {
        pa.W[i] = (const float*)d_in[widx[i]];
        pa.H[i] = GH[wplane[i]];
        pa.L[i] = GL[wplane[i]];
        pa.koff[i] = wkoff[i];
        pa.nshift[i] = wnsh[i];
        acc_end += welem[i];
        pa.end[i] = acc_end;
    }

    int* ioff = (int*)(((size_t)W + 15) & ~(size_t)15);
    int* icnt = ioff + ((N + 1 + 3) & ~3);
    int* icur = icnt + ((N + 3) & ~3);
    int* csr  = icur + ((N + 3) & ~3);
    int* bsum = csr + ((E + 3) & ~3);

    const int NBLK = (N + 1023) / 1024;

    hipMemsetAsync(icnt, 0, (size_t)N * sizeof(int), stream);
    hipMemsetAsync(icur, 0, (size_t)N * sizeof(int), stream);
    hist_kernel<<<(E + 255) / 256, 256, 0, stream>>>(dst, icnt, E);
    scan_part<<<NBLK, 256, 0, stream>>>(icnt, bsum, N);
    scan_top<<<1, 64, 0, stream>>>(bsum, NBLK);
    scan_final<<<NBLK, 256, 0, stream>>>(icnt, bsum, ioff, N, E);
    scatter_kernel<<<(E + 255) / 256, 256, 0, stream>>>(src, dst, icur, ioff, csr, E);
    prep_weights<<<(acc_end + 255) / 256, 256, 0, stream>>>(pa, acc_end);

    const int GB2 = (M_pad / 128) * 2;   // 784 blocks (NB=256, 2 col-blocks)
    const int GB1 = M_pad / 128;         // 392 blocks (NB=128)
    const int GA = (N + 3) / 4;

    // stem
    gemm_pipe<16, 0, true, 256, false><<<GB2, 256, 0, stream>>>(
        feat, nullptr, nullptr, GH[0], GL[0], b1, P0, nullptr, N);
    gemm_pipe<8, 0, false, 256, false><<<GB2, 256, 0, stream>>>(
        nullptr, P0, nullptr, GH[1], GL[1], b2, P1, nullptr, N);
    gemm_pipe<8, 0, false, 256, false><<<GB2, 256, 0, stream>>>(
        nullptr, P1, nullptr, GH[2], GL[2], b3, P0, nullptr, N);

    // SAGE 1: x = P0
    sage_aggr_pk<<<GA, 256, 0, stream>>>(P0, csr, ioff, P1, N);
    gemm_pipe<8, 8, false, 256, false><<<GB2, 256, 0, stream>>>(
        nullptr, P1, P0, GH[3], GL[3], bl1, P2, nullptr, N);

    // SAGE 2: x = P2
    sage_aggr_pk<<<GA, 256, 0, stream>>>(P2, csr, ioff, P1, N);
    gemm_pipe<8, 8, false, 256, false><<<GB2, 256, 0, stream>>>(
        nullptr, P1, P2, GH[4], GL[4], blH, P0, nullptr, N);

    // SAGE 3: x = P0
    sage_aggr_pk<<<GA, 256, 0, stream>>>(P0, csr, ioff, P1, N);
    gemm_pipe<8, 8, false, 256, false><<<GB2, 256, 0, stream>>>(
        nullptr, P1, P0, GH[5], GL[5], bl2, P2, nullptr, N);

    // head
    gemm_pipe<8, 0, false, 256, false><<<GB2, 256, 0, stream>>>(
        nullptr, P2, nullptr, GH[6], GL[6], bp1, P0, nullptr, N);
    gemm_pipe<8, 0, false, 256, false><<<GB2, 256, 0, stream>>>(
        nullptr, P0, nullptr, GH[7], GL[7], bp2, P1, nullptr, N);
    gemm_pipe<8, 0, false, 128, true><<<GB1, 256, 0, stream>>>(
        nullptr, P1, nullptr, GH[8], GL[8], bp3, nullptr, (float*)d_out, N);
}

// Round 16
// 614.171 us; speedup vs baseline: 1.2286x; 1.2286x over previous
//
#include <hip/hip_runtime.h>
#include <hip/hip_bf16.h>
#include <math.h>

typedef short s8v __attribute__((ext_vector_type(8)));
typedef float f32x4 __attribute__((ext_vector_type(4)));
typedef unsigned u32x4 __attribute__((ext_vector_type(4)));

__device__ __forceinline__ ushort f2bf(float f) {
    __hip_bfloat16 h = __float2bfloat16(f);
    return *reinterpret_cast<ushort*>(&h);
}
__device__ __forceinline__ float bf2f(ushort u) {
    return __uint_as_float(((unsigned)u) << 16);
}
__device__ __forceinline__ unsigned pack_split(float v) {
    ushort h = f2bf(v);
    ushort l = f2bf(v - bf2f(h));
    return ((unsigned)h << 16) | (unsigned)l;
}
__device__ __forceinline__ float unpack_f(unsigned p) {
    return __uint_as_float(p & 0xffff0000u) + __uint_as_float(p << 16);
}
__device__ __forceinline__ void gload16(const void* g, void* l) {
    __builtin_amdgcn_global_load_lds(
        (const __attribute__((address_space(1))) void*)g,
        (__attribute__((address_space(3))) void*)l, 16, 0, 0);
}
__device__ __forceinline__ unsigned lds_addr(const void* p) {
    return (unsigned)(size_t)(const __attribute__((address_space(3))) void*)p;
}
// 8 packed u32 (k0..7) -> hi frag / lo frag
__device__ __forceinline__ void unpack8(const u32x4 p0, const u32x4 p1, s8v& hi, s8v& lo) {
    union { s8v v; unsigned u[4]; } H, L;
    H.u[0] = (p0[0] >> 16) | (p0[1] & 0xffff0000u);
    H.u[1] = (p0[2] >> 16) | (p0[3] & 0xffff0000u);
    H.u[2] = (p1[0] >> 16) | (p1[1] & 0xffff0000u);
    H.u[3] = (p1[2] >> 16) | (p1[3] & 0xffff0000u);
    L.u[0] = (p0[0] & 0xffffu) | (p0[1] << 16);
    L.u[1] = (p0[2] & 0xffffu) | (p0[3] << 16);
    L.u[2] = (p1[0] & 0xffffu) | (p1[1] << 16);
    L.u[3] = (p1[2] & 0xffffu) | (p1[3] << 16);
    hi = H.v; lo = L.v;
}
// 8 fp32 -> hi/lo bf16 frags (stem GEMM1 only)
__device__ __forceinline__ void cvt8(const u32x4 p0, const u32x4 p1, s8v& hi, s8v& lo) {
    union { s8v v; ushort e[8]; } H, L;
    float f[8] = {__uint_as_float(p0[0]), __uint_as_float(p0[1]),
                  __uint_as_float(p0[2]), __uint_as_float(p0[3]),
                  __uint_as_float(p1[0]), __uint_as_float(p1[1]),
                  __uint_as_float(p1[2]), __uint_as_float(p1[3])};
    #pragma unroll
    for (int e = 0; e < 8; ++e) {
        ushort h = f2bf(f[e]);
        H.e[e] = (ushort)h;
        L.e[e] = f2bf(f[e] - bf2f(h));
    }
    hi = H.v; lo = L.v;
}
template<bool AF32>
__device__ __forceinline__ void frag_a(const u32x4 p0, const u32x4 p1, s8v& hi, s8v& lo) {
    if constexpr (AF32) cvt8(p0, p1, hi, lo);
    else                unpack8(p0, p1, hi, lo);
}

#define DSR(dst, addr, OFF) \
    asm volatile("ds_read_b128 %0, %1 offset:" #OFF : "=v"(dst) : "v"(addr))

// B fragment direct from global (L2-resident weights), SGPR base + VGPR voffset
#define GLB(dst, voff, base, OFF) \
    asm volatile("global_load_dwordx4 %0, %1, %2 offset:" #OFF \
                 : "=v"(dst) : "v"(voff), "s"(base))

#define TRI(ah, al, bh, bl, C) \
    C = __builtin_amdgcn_mfma_f32_16x16x32_bf16(ah, bh, C, 0, 0, 0); \
    C = __builtin_amdgcn_mfma_f32_16x16x32_bf16(ah, bl, C, 0, 0, 0); \
    C = __builtin_amdgcn_mfma_f32_16x16x32_bf16(al, bh, C, 0, 0, 0);

// ---------------- CSR build ----------------

__global__ __launch_bounds__(256)
void hist_kernel(const int* __restrict__ dst, int* __restrict__ cnt, int E) {
    int e = blockIdx.x * 256 + threadIdx.x;
    if (e < E) atomicAdd(&cnt[dst[e]], 1);
}

__global__ __launch_bounds__(256)
void scan_part(const int* __restrict__ cnt, int* __restrict__ bsum, int n) {
    __shared__ int s[256];
    int b = blockIdx.x, t = threadIdx.x;
    int i0 = b * 1024 + t * 4;
    int v = 0;
    if (i0 + 3 < n) {
        int4 q = *(const int4*)(cnt + i0);
        v = q.x + q.y + q.z + q.w;
    } else {
        for (int i = 0; i < 4; ++i) if (i0 + i < n) v += cnt[i0 + i];
    }
    s[t] = v;
    __syncthreads();
    for (int d = 128; d > 0; d >>= 1) {
        if (t < d) s[t] += s[t + d];
        __syncthreads();
    }
    if (t == 0) bsum[b] = s[0];
}

__global__ __launch_bounds__(64)
void scan_top(int* __restrict__ bsum, int nb) {
    int l = threadIdx.x;
    int own = (l < nb) ? bsum[l] : 0;
    int v = own;
    #pragma unroll
    for (int d = 1; d < 64; d <<= 1) {
        int u = __shfl_up(v, d, 64);
        if (l >= d) v += u;
    }
    if (l < nb) bsum[l] = v - own;   // exclusive
}

__global__ __launch_bounds__(256)
void scan_final(const int* __restrict__ cnt, const int* __restrict__ bsum,
                int* __restrict__ off, int n, int E) {
    __shared__ int s[256];
    int b = blockIdx.x, t = threadIdx.x;
    int i0 = b * 1024 + t * 4;
    int v0 = 0, v1 = 0, v2 = 0, v3 = 0;
    if (i0 + 3 < n) {
        int4 q = *(const int4*)(cnt + i0);
        v0 = q.x; v1 = q.y; v2 = q.z; v3 = q.w;
    } else {
        if (i0     < n) v0 = cnt[i0];
        if (i0 + 1 < n) v1 = cnt[i0 + 1];
        if (i0 + 2 < n) v2 = cnt[i0 + 2];
        if (i0 + 3 < n) v3 = cnt[i0 + 3];
    }
    int tsum = v0 + v1 + v2 + v3;
    s[t] = tsum;
    __syncthreads();
    for (int d = 1; d < 256; d <<= 1) {
        int u = (t >= d) ? s[t - d] : 0;
        __syncthreads();
        s[t] += u;
        __syncthreads();
    }
    int excl = s[t] - tsum + bsum[b];
    if (i0     < n) off[i0]     = excl;
    if (i0 + 1 < n) off[i0 + 1] = excl + v0;
    if (i0 + 2 < n) off[i0 + 2] = excl + v0 + v1;
    if (i0 + 3 < n) off[i0 + 3] = excl + v0 + v1 + v2;
    if (b == 0 && t == 0) off[n] = E;
}

__global__ __launch_bounds__(256)
void scatter_kernel(const int* __restrict__ src, const int* __restrict__ dst,
                    int* __restrict__ cur, const int* __restrict__ off,
                    int* __restrict__ csr, int E) {
    int e = blockIdx.x * 256 + threadIdx.x;
    if (e < E) {
        int d = dst[e];
        int pos = off[d] + atomicAdd(&cur[d], 1);
        csr[pos] = src[e];
    }
}

// ------- weight prep: planar-chunked hi/lo bf16, [k/8][n][8], concat along K --

struct PrepW {
    const float* W[12];
    ushort* H[12];
    ushort* L[12];
    int end[12];
    int koff[12];
    int nshift[12];
};

__global__ __launch_bounds__(256)
void prep_weights(PrepW a, int total) {
    int id = blockIdx.x * 256 + threadIdx.x;
    if (id >= total) return;
    int s = 0;
    #pragma unroll
    for (int i = 0; i < 12; ++i) if (id >= a.end[i]) s = i + 1;
    int base = (s == 0) ? 0 : a.end[s - 1];
    int e = id - base;
    int Nmask = (1 << a.nshift[s]) - 1;
    int n = e & Nmask;
    int k = e >> a.nshift[s];
    float w = a.W[s][(size_t)k * (Nmask + 1) + n];
    ushort hi = f2bf(w);
    int kp = a.koff[s] + k;
    size_t idx = ((size_t)(kp >> 3) * (Nmask + 1) + n) * 8 + (kp & 7);
    a.H[s][idx] = hi;
    a.L[s][idx] = f2bf(w - bf2f(hi));
}

// ---------------- per-dst softmax aggregation (packed u32, direct exp) -------
// 2-edge unroll with dual independent accumulator sets (breaks the serial
// per-edge add/fma chain; overlaps second gather with first edge's VALU).

__global__ __launch_bounds__(256)
void sage_aggr_pk(const unsigned* __restrict__ X, const int* __restrict__ csr,
                  const int* __restrict__ off, unsigned* __restrict__ O, int nN) {
    int node = blockIdx.x * 4 + (threadIdx.x >> 6);
    if (node >= nN) return;
    int c4 = (threadIdx.x & 63) * 4;
    int s0 = off[node], s1 = off[node + 1];
    float seA0 = 0, seA1 = 0, seA2 = 0, seA3 = 0;
    float smA0 = 0, smA1 = 0, smA2 = 0, smA3 = 0;
    float seB0 = 0, seB1 = 0, seB2 = 0, seB3 = 0;
    float smB0 = 0, smB1 = 0, smB2 = 0, smB3 = 0;
    int j = s0;
    for (; j + 2 <= s1; j += 2) {
        uint4 pa = *(const uint4*)(X + (size_t)csr[j] * 256 + c4);
        uint4 pb = *(const uint4*)(X + (size_t)csr[j + 1] * 256 + c4);
        float a0 = unpack_f(pa.x), a1 = unpack_f(pa.y), a2 = unpack_f(pa.z), a3 = unpack_f(pa.w);
        float b0 = unpack_f(pb.x), b1 = unpack_f(pb.y), b2 = unpack_f(pb.z), b3 = unpack_f(pb.w);
        float ea0 = __expf(fminf(a0, 60.f)), ea1 = __expf(fminf(a1, 60.f));
        float ea2 = __expf(fminf(a2, 60.f)), ea3 = __expf(fminf(a3, 60.f));
        float eb0 = __expf(fminf(b0, 60.f)), eb1 = __expf(fminf(b1, 60.f));
        float eb2 = __expf(fminf(b2, 60.f)), eb3 = __expf(fminf(b3, 60.f));
        seA0 += ea0; smA0 = fmaf(a0, ea0, smA0);
        seA1 += ea1; smA1 = fmaf(a1, ea1, smA1);
        seA2 += ea2; smA2 = fmaf(a2, ea2, smA2);
        seA3 += ea3; smA3 = fmaf(a3, ea3, smA3);
        seB0 += eb0; smB0 = fmaf(b0, eb0, smB0);
        seB1 += eb1; smB1 = fmaf(b1, eb1, smB1);
        seB2 += eb2; smB2 = fmaf(b2, eb2, smB2);
        seB3 += eb3; smB3 = fmaf(b3, eb3, smB3);
    }
    if (j < s1) {
        uint4 pa = *(const uint4*)(X + (size_t)csr[j] * 256 + c4);
        float a0 = unpack_f(pa.x), a1 = unpack_f(pa.y), a2 = unpack_f(pa.z), a3 = unpack_f(pa.w);
        float ea0 = __expf(fminf(a0, 60.f)), ea1 = __expf(fminf(a1, 60.f));
        float ea2 = __expf(fminf(a2, 60.f)), ea3 = __expf(fminf(a3, 60.f));
        seA0 += ea0; smA0 = fmaf(a0, ea0, smA0);
        seA1 += ea1; smA1 = fmaf(a1, ea1, smA1);
        seA2 += ea2; smA2 = fmaf(a2, ea2, smA2);
        seA3 += ea3; smA3 = fmaf(a3, ea3, smA3);
    }
    float se0 = seA0 + seB0, se1 = seA1 + seB1, se2 = seA2 + seB2, se3 = seA3 + seB3;
    float sm0 = smA0 + smB0, sm1 = smA1 + smB1, sm2 = smA2 + smB2, sm3 = smA3 + smB3;
    uint4 o;
    o.x = pack_split((s1 > s0) ? sm0 / se0 : 0.f);
    o.y = pack_split((s1 > s0) ? sm1 / se1 : 0.f);
    o.z = pack_split((s1 > s0) ? sm2 / se2 : 0.f);
    o.w = pack_split((s1 > s0) ? sm3 / se3 : 0.f);
    *(uint4*)(O + (size_t)node * 256 + c4) = o;
}

// ---------------- split-bf16 MFMA GEMM: A via LDS (3 bufs), B global->reg -----
// Round-12 champion structure, FROZEN byte-for-byte (626 us, validated):
// BM=128, BN=128, BK=32, 256 threads (4 waves), 3 LDS bufs x 16KB (A only)
// -> 3 blocks/CU, depth-2 A prefetch, B planar-chunked [k/8][n][8] straight
// to regs. Publish ordering: A(t+2) writes drained by own vmcnt(4) at
// mid-step t+1, published by barrier at top of t+2.

template<int NT1, int NT2, bool AF32, int NB, bool DOTANH>
__global__ __launch_bounds__(256, 3)
void gemm_pipe(const float* __restrict__ Af,
               const unsigned* __restrict__ A1, const unsigned* __restrict__ A2,
               const ushort* __restrict__ BH, const ushort* __restrict__ BL,
               const float* __restrict__ bias,
               unsigned* __restrict__ Cpk, float* __restrict__ Cf, int M) {
    constexpr int NT = NT1 + NT2;
    constexpr int KU = NT * 32;
    constexpr int NCB = NB / 128;
    constexpr unsigned DSTEP = 4u * NB * 16u;   // bv advance per K-step (bytes)
    __shared__ unsigned lds[3][4096];           // 3 x 16KB, A only

    const int tid = threadIdx.x;
    const int l = tid & 63;
    const int w = tid >> 6;               // 0..3
    const int wm = w >> 1, wn = w & 1;
    const int li = l & 15, kq = l >> 4;
    const int b = blockIdx.x;
    const int bm = (b / NCB) * 128;
    const int bn = (b % NCB) * 128;

    const int srow8 = l >> 3;
    const int schunk = (l & 7) ^ srow8;   // swizzled source k-chunk

    const unsigned lbase = lds_addr(&lds[0][0]);
    const unsigned aoff = (unsigned)((wm * 64 + li) * 128 + (((2 * kq) ^ (li & 7)) * 16));

    f32x4 acc[4][4];
    #pragma unroll
    for (int i = 0; i < 4; ++i)
        #pragma unroll
        for (int j = 0; j < 4; ++j) acc[i][j] = (f32x4){0.f, 0.f, 0.f, 0.f};

    auto STAGE = [&](int t, int buf) {
        #pragma unroll
        for (int s = 0; s < 4; ++s) {         // A: 128 rows, wave w owns 32
            int r = 32 * w + 8 * s + srow8;
            int gr = bm + r; gr = (gr < M) ? gr : (M - 1);
            const void* src;
            if constexpr (AF32) {
                src = Af + (size_t)gr * KU + t * 32 + schunk * 4;
            } else if constexpr (NT2 > 0) {
                src = (t < NT1) ? (const void*)(A1 + (size_t)gr * (NT1 * 32) + t * 32 + schunk * 4)
                                : (const void*)(A2 + (size_t)gr * (NT2 * 32) + (t - NT1) * 32 + schunk * 4);
            } else {
                src = A1 + (size_t)gr * KU + t * 32 + schunk * 4;
            }
            gload16(src, &lds[buf][(32 * w + 8 * s) * 32 + l * 4]);
        }
    };

    // B voffset: element (kchunk*NB + n) * 16B; kchunk = t*4 + kq
    unsigned bv = (unsigned)((kq * NB + bn + wn * 64 + li) * 16);
    s8v bh0, bh1, bh2, bh3, bl0, bl1, bl2, bl3;

    // prologue: A(0), A(1) staged; B(0) in flight
    STAGE(0, 0);
    STAGE(1, 1);
    GLB(bh0, bv, BH, 0);   GLB(bh1, bv, BH, 256);
    GLB(bh2, bv, BH, 512); GLB(bh3, bv, BH, 768);
    GLB(bl0, bv, BL, 0);   GLB(bl1, bv, BL, 256);
    GLB(bl2, bv, BL, 512); GLB(bl3, bv, BL, 768);
    bv += DSTEP;
    asm volatile("s_waitcnt vmcnt(8)" ::: "memory");   // A(0),A(1) landed; B(0) flies
    __builtin_amdgcn_sched_barrier(0);

    #pragma unroll
    for (int t = 0; t < NT; ++t) {
        __builtin_amdgcn_s_barrier();

        const int buf = t % 3;
        unsigned ab = lbase + (unsigned)buf * 16384u + aoff;
        unsigned ab1 = ab ^ 16u;

        u32x4 A0, A4, A1v, A5, A2v, A6, A3, A7;
        DSR(A0, ab, 0); DSR(A4, ab1, 0);
        __builtin_amdgcn_sched_barrier(0);

        if (t + 2 < NT) STAGE(t + 2, (t + 2) % 3);
        __builtin_amdgcn_sched_barrier(0);

        DSR(A1v, ab, 2048); DSR(A5, ab1, 2048);
        // drain B(t) (+A(t+1)); keep A(t+2) in flight; A0/A4 returned
        if (t + 2 < NT) asm volatile("s_waitcnt vmcnt(4) lgkmcnt(2)" ::: "memory");
        else            asm volatile("s_waitcnt vmcnt(0) lgkmcnt(2)" ::: "memory");
        __builtin_amdgcn_sched_barrier(0);

        __builtin_amdgcn_s_setprio(1);
        {
            s8v ah, al;
            frag_a<AF32>(A0, A4, ah, al);
            TRI(ah, al, bh0, bl0, acc[0][0]) TRI(ah, al, bh1, bl1, acc[0][1])
            TRI(ah, al, bh2, bl2, acc[0][2]) TRI(ah, al, bh3, bl3, acc[0][3])
        }
        __builtin_amdgcn_sched_barrier(0);
        DSR(A2v, ab, 4096); DSR(A6, ab1, 4096);
        asm volatile("s_waitcnt lgkmcnt(2)" ::: "memory");
        __builtin_amdgcn_sched_barrier(0);
        {
            s8v ah, al;
            frag_a<AF32>(A1v, A5, ah, al);
            TRI(ah, al, bh0, bl0, acc[1][0]) TRI(ah, al, bh1, bl1, acc[1][1])
            TRI(ah, al, bh2, bl2, acc[1][2]) TRI(ah, al, bh3, bl3, acc[1][3])
        }
        __builtin_amdgcn_sched_barrier(0);
        DSR(A3, ab, 6144); DSR(A7, ab1, 6144);
        asm volatile("s_waitcnt lgkmcnt(2)" ::: "memory");
        __builtin_amdgcn_sched_barrier(0);
        {
            s8v ah, al;
            frag_a<AF32>(A2v, A6, ah, al);
            TRI(ah, al, bh0, bl0, acc[2][0]) TRI(ah, al, bh1, bl1, acc[2][1])
            TRI(ah, al, bh2, bl2, acc[2][2]) TRI(ah, al, bh3, bl3, acc[2][3])
        }
        asm volatile("s_waitcnt lgkmcnt(0)" ::: "memory");
        __builtin_amdgcn_sched_barrier(0);
        {
            s8v ah, al;
            frag_a<AF32>(A3, A7, ah, al);
            TRI(ah, al, bh0, bl0, acc[3][0]) TRI(ah, al, bh1, bl1, acc[3][1])
            TRI(ah, al, bh2, bl2, acc[3][2]) TRI(ah, al, bh3, bl3, acc[3][3])
        }
        __builtin_amdgcn_s_setprio(0);
        __builtin_amdgcn_sched_barrier(0);

        if (t + 1 < NT) {   // issue B(t+1); lands before next step's vmcnt(4)
            GLB(bh0, bv, BH, 0);   GLB(bh1, bv, BH, 256);
            GLB(bh2, bv, BH, 512); GLB(bh3, bv, BH, 768);
            GLB(bl0, bv, BL, 0);   GLB(bl1, bv, BL, 256);
            GLB(bl2, bv, BL, 512); GLB(bl3, bv, BL, 768);
            bv += DSTEP;
        }
    }

    // epilogue. C frag: col = lane&15, row = (lane>>4)*4 + reg
    #pragma unroll
    for (int j = 0; j < 4; ++j) {
        int col = bn + wn * 64 + 16 * j + li;
        float bb = bias[col];
        #pragma unroll
        for (int i = 0; i < 4; ++i) {
            int row0 = bm + wm * 64 + 16 * i + kq * 4;
            #pragma unroll
            for (int r = 0; r < 4; ++r) {
                float v = acc[i][j][r] + bb;
                if constexpr (DOTANH) {
                    if (row0 + r < M)
                        Cf[(size_t)(row0 + r) * NB + col] = tanhf(v);
                } else {
                    Cpk[(size_t)(row0 + r) * 256 + col] = pack_split(fmaxf(v, 0.f));
                }
            }
        }
    }
}

// ---------------- launch ----------------

extern "C" void kernel_launch(void* const* d_in, const int* in_sizes, int n_in,
                              void* d_out, int out_size, void* d_ws, size_t ws_size,
                              hipStream_t stream) {
    const float* feat = (const float*)d_in[0];
    const int* einfo = (const int*)d_in[1];
    const float* b1 = (const float*)d_in[3];
    const float* b2 = (const float*)d_in[5];
    const float* b3 = (const float*)d_in[7];
    const float* bl1 = (const float*)d_in[9];
    const float* blH = (const float*)d_in[12];
    const float* bl2 = (const float*)d_in[15];
    const float* bp1 = (const float*)d_in[18];
    const float* bp2 = (const float*)d_in[20];
    const float* bp3 = (const float*)d_in[22];

    const int IN_DIM = 512;
    const int N = in_sizes[0] / IN_DIM;   // 50000
    const int E = in_sizes[1] / 2;        // 400000
    const int* src = einfo;
    const int* dst = einfo + E;
    const int M_pad = ((N + 127) / 128) * 128;      // 50176
    const size_t PLANE_U = (size_t)M_pad * 256;

    unsigned* P0 = (unsigned*)d_ws;
    unsigned* P1 = P0 + PLANE_U;
    unsigned* P2 = P1 + PLANE_U;
    ushort* W = (ushort*)(P2 + PLANE_U);

    // planar-chunked weight planes (concat along K for fused SAGE GEMMs)
    const int gsz[9] = {131072, 65536, 65536, 131072, 131072, 131072, 65536, 65536, 32768};
    ushort* GH[9]; ushort* GL[9];
    for (int i = 0; i < 9; ++i) { GH[i] = W; W += gsz[i]; GL[i] = W; W += gsz[i]; }

    const int widx[12]   = {2, 4, 6, 8, 10, 11, 13, 14, 16, 17, 19, 21};
    const int wplane[12] = {0, 1, 2, 3, 3, 4, 4, 5, 5, 6, 7, 8};
    const int wkoff[12]  = {0, 0, 0, 0, 256, 0, 256, 0, 256, 0, 0, 0};
    const int wnsh[12]   = {8, 8, 8, 8, 8, 8, 8, 8, 8, 8, 8, 7};
    const int welem[12]  = {131072, 65536, 65536, 65536, 65536, 65536, 65536,
                            65536, 65536, 65536, 65536, 32768};

    PrepW pa;
    int acc_end = 0;
    for (int i = 0; i < 12; ++i) {
        pa.W[i] = (const float*)d_in[widx[i]];
        pa.H[i] = GH[wplane[i]];
        pa.L[i] = GL[wplane[i]];
        pa.koff[i] = wkoff[i];
        pa.nshift[i] = wnsh[i];
        acc_end += welem[i];
        pa.end[i] = acc_end;
    }

    int* ioff = (int*)(((size_t)W + 15) & ~(size_t)15);
    int* icnt = ioff + ((N + 1 + 3) & ~3);
    int* icur = icnt + ((N + 3) & ~3);
    int* csr  = icur + ((N + 3) & ~3);
    int* bsum = csr + ((E + 3) & ~3);

    const int NBLK = (N + 1023) / 1024;

    hipMemsetAsync(icnt, 0, (size_t)N * sizeof(int), stream);
    hipMemsetAsync(icur, 0, (size_t)N * sizeof(int), stream);
    hist_kernel<<<(E + 255) / 256, 256, 0, stream>>>(dst, icnt, E);
    scan_part<<<NBLK, 256, 0, stream>>>(icnt, bsum, N);
    scan_top<<<1, 64, 0, stream>>>(bsum, NBLK);
    scan_final<<<NBLK, 256, 0, stream>>>(icnt, bsum, ioff, N, E);
    scatter_kernel<<<(E + 255) / 256, 256, 0, stream>>>(src, dst, icur, ioff, csr, E);
    prep_weights<<<(acc_end + 255) / 256, 256, 0, stream>>>(pa, acc_end);

    const int GB2 = (M_pad / 128) * 2;   // 784 blocks (NB=256, 2 col-blocks)
    const int GB1 = M_pad / 128;         // 392 blocks (NB=128)
    const int GA = (N + 3) / 4;

    // stem
    gemm_pipe<16, 0, true, 256, false><<<GB2, 256, 0, stream>>>(
        feat, nullptr, nullptr, GH[0], GL[0], b1, P0, nullptr, N);
    gemm_pipe<8, 0, false, 256, false><<<GB2, 256, 0, stream>>>(
        nullptr, P0, nullptr, GH[1], GL[1], b2, P1, nullptr, N);
    gemm_pipe<8, 0, false, 256, false><<<GB2, 256, 0, stream>>>(
        nullptr, P1, nullptr, GH[2], GL[2], b3, P0, nullptr, N);

    // SAGE 1: x = P0
    sage_aggr_pk<<<GA, 256, 0, stream>>>(P0, csr, ioff, P1, N);
    gemm_pipe<8, 8, false, 256, false><<<GB2, 256, 0, stream>>>(
        nullptr, P1, P0, GH[3], GL[3], bl1, P2, nullptr, N);

    // SAGE 2: x = P2
    sage_aggr_pk<<<GA, 256, 0, stream>>>(P2, csr, ioff, P1, N);
    gemm_pipe<8, 8, false, 256, false><<<GB2, 256, 0, stream>>>(
        nullptr, P1, P2, GH[4], GL[4], blH, P0, nullptr, N);

    // SAGE 3: x = P0
    sage_aggr_pk<<<GA, 256, 0, stream>>>(P0, csr, ioff, P1, N);
    gemm_pipe<8, 8, false, 256, false><<<GB2, 256, 0, stream>>>(
        nullptr, P1, P0, GH[5], GL[5], bl2, P2, nullptr, N);

    // head
    gemm_pipe<8, 0, false, 256, false><<<GB2, 256, 0, stream>>>(
        nullptr, P2, nullptr, GH[6], GL[6], bp1, P0, nullptr, N);
    gemm_pipe<8, 0, false, 256, false><<<GB2, 256, 0, stream>>>(
        nullptr, P0, nullptr, GH[7], GL[7], bp2, P1, nullptr, N);
    gemm_pipe<8, 0, false, 128, true><<<GB1, 256, 0, stream>>>(
        nullptr, P1, nullptr, GH[8], GL[8], bp3, nullptr, (float*)d_out, N);
}